// Round 6
// baseline (789.076 us; speedup 1.0000x reference)
//
#include <hip/hip_runtime.h>
#include <hip/hip_bf16.h>

// Nystroem: out = exp(-gamma * (||x||^2 + ||c||^2 - 2 X C^T)) @ Wn
// N=16384, D=2048, C=2048, all fp32 in/out.
//
// Pipeline:
//   prep_rows(X)   -> Xb (bf16), x_sq (fp32)
//   prep_rows(Cen) -> Cb (bf16), c_sq (fp32)
//   prep_wt(Wn)    -> WTh/WTl (bf16 hi/lo, TRANSPOSED so GEMM2 is B^T form)
//   gemm1: S = Xb @ Cb^T (bf16 MFMA), epilogue P=exp(-g*dist) -> Ph/Pl (hi/lo)
//   gemm2: out = Ph*WTh + Ph*WTl + Pl*WTh (split-bf16 3-pass, ~fp32 accuracy)

#define N_ROWS 16384
#define D_DIM  2048
#define C_DIM  2048

typedef __attribute__((ext_vector_type(4))) float f32x4;
typedef __attribute__((ext_vector_type(8))) short bf16x8;
typedef __attribute__((ext_vector_type(8))) unsigned short ushort8;

__device__ __forceinline__ unsigned short f2bf(float f) {
  unsigned int u = __float_as_uint(f);
  u += 0x7FFFu + ((u >> 16) & 1u);   // RNE
  return (unsigned short)(u >> 16);
}
__device__ __forceinline__ float bf2f(unsigned short h) {
  return __uint_as_float(((unsigned int)h) << 16);
}
__device__ __forceinline__ void load_lds16(const void* g, void* l) {
  __builtin_amdgcn_global_load_lds(
      (const __attribute__((address_space(1))) unsigned int*)g,
      (__attribute__((address_space(3))) unsigned int*)l, 16, 0, 0);
}

// One block per row of `src` (ncols=2048): write bf16 row + sum of squares.
__global__ void prep_rows(const float* __restrict__ src,
                          unsigned short* __restrict__ dst,
                          float* __restrict__ sq) {
  const int row = blockIdx.x;
  const int t = threadIdx.x;
  const float* p = src + (size_t)row * D_DIM + t * 8;
  float4 v0 = ((const float4*)p)[0];
  float4 v1 = ((const float4*)p)[1];
  float vals[8] = {v0.x, v0.y, v0.z, v0.w, v1.x, v1.y, v1.z, v1.w};
  float ss = 0.f;
  ushort8 h;
#pragma unroll
  for (int j = 0; j < 8; ++j) {
    ss += vals[j] * vals[j];
    h[j] = f2bf(vals[j]);
  }
  *(ushort8*)(dst + (size_t)row * D_DIM + t * 8) = h;
  // block reduce ss
  __shared__ float red[4];
  const int lane = t & 63, wave = t >> 6;
#pragma unroll
  for (int off = 32; off > 0; off >>= 1) ss += __shfl_down(ss, off);
  if (lane == 0) red[wave] = ss;
  __syncthreads();
  if (t == 0) sq[row] = red[0] + red[1] + red[2] + red[3];
}

// Transpose + hi/lo split of normalization: WT[j][c] = split(W[c][j]).
__global__ void prep_wt(const float* __restrict__ W,
                        unsigned short* __restrict__ WTh,
                        unsigned short* __restrict__ WTl) {
  __shared__ float tile[64][65];
  const int bc = blockIdx.x >> 5;   // c-tile (rows of W)
  const int bj = blockIdx.x & 31;   // j-tile (cols of W)
  const int t = threadIdx.x;
#pragma unroll
  for (int i = 0; i < 16; ++i) {
    int idx = i * 256 + t;
    int r = idx >> 6, c = idx & 63;
    tile[r][c] = W[(size_t)(bc * 64 + r) * C_DIM + bj * 64 + c];
  }
  __syncthreads();
#pragma unroll
  for (int i = 0; i < 16; ++i) {
    int idx = i * 256 + t;
    int r2 = idx >> 6, c2 = idx & 63;   // r2: j index, c2: c index
    float w = tile[c2][r2];
    unsigned short h = f2bf(w);
    unsigned short l = f2bf(w - bf2f(h));
    size_t o = (size_t)(bj * 64 + r2) * C_DIM + bc * 64 + c2;
    WTh[o] = h;
    WTl[o] = l;
  }
}

// GEMM1: 128x128 tile, BK=64, 4 waves, 16x16x32 bf16 MFMA.
// A = Xb [N][K], B^T = Cb [C][K]. Epilogue: P = exp(-g*dist) -> Ph/Pl.
__global__ __launch_bounds__(256, 2) void gemm1(
    const unsigned short* __restrict__ Xb, const unsigned short* __restrict__ Cb,
    const float* __restrict__ x_sq, const float* __restrict__ c_sq,
    const float* __restrict__ gamma,
    unsigned short* __restrict__ Ph, unsigned short* __restrict__ Pl) {
  constexpr int K = D_DIM;
  __shared__ unsigned short As[128 * 64];
  __shared__ unsigned short Bs[128 * 64];
  const int tid = threadIdx.x;
  const int lane = tid & 63, wave = tid >> 6;
  const int wr = wave >> 1, wc = wave & 1;
  // XCD-aware swizzle: nwg=2048, 8 XCDs, chunk=256 (bijective: 2048%8==0)
  const int nwg = gridDim.x;
  const int cpx = nwg >> 3;
  const int wgid = (blockIdx.x & 7) * cpx + (blockIdx.x >> 3);
  const int bcol = wgid & 15;
  const int brow = wgid >> 4;
  const int fr = lane & 15, fq = lane >> 4;
  f32x4 acc[4][4] = {};
  const float g = gamma[0];

  const char* Abase = (const char*)(Xb + (size_t)brow * 128 * K);
  const char* Bbase = (const char*)(Cb + (size_t)bcol * 128 * K);
  for (int kt = 0; kt < K; kt += 64) {
#pragma unroll
    for (int r = 0; r < 4; ++r) {
      int base = r * 4096 + wave * 1024;  // wave-uniform LDS byte offset
      int bo = base + lane * 16;
      int row = bo >> 7;        // 128 B per row (64 bf16)
      int inrow = bo & 127;
      load_lds16(Abase + (size_t)row * K * 2 + kt * 2 + inrow, (char*)As + base);
      load_lds16(Bbase + (size_t)row * K * 2 + kt * 2 + inrow, (char*)Bs + base);
    }
    __syncthreads();
#pragma unroll
    for (int ks = 0; ks < 64; ks += 32) {
      bf16x8 af[4], bfr[4];
#pragma unroll
      for (int m = 0; m < 4; ++m)
        af[m] = *(const bf16x8*)&As[(wr * 64 + m * 16 + fr) * 64 + ks + fq * 8];
#pragma unroll
      for (int n = 0; n < 4; ++n)
        bfr[n] = *(const bf16x8*)&Bs[(wc * 64 + n * 16 + fr) * 64 + ks + fq * 8];
#pragma unroll
      for (int m = 0; m < 4; ++m)
#pragma unroll
        for (int n = 0; n < 4; ++n)
          acc[m][n] = __builtin_amdgcn_mfma_f32_16x16x32_bf16(af[m], bfr[n], acc[m][n], 0, 0, 0);
    }
    __syncthreads();
  }
  // epilogue: dist -> exp -> hi/lo bf16
#pragma unroll
  for (int m = 0; m < 4; ++m) {
#pragma unroll
    for (int i = 0; i < 4; ++i) {
      int grow = brow * 128 + wr * 64 + m * 16 + fq * 4 + i;
      float xs = x_sq[grow];
#pragma unroll
      for (int n = 0; n < 4; ++n) {
        int gcol = bcol * 128 + wc * 64 + n * 16 + fr;
        float s = acc[m][n][i];
        float dist = xs + c_sq[gcol] - 2.0f * s;
        float p = __expf(-g * dist);
        unsigned short h = f2bf(p);
        unsigned short l = f2bf(p - bf2f(h));
        size_t o = (size_t)grow * C_DIM + gcol;
        Ph[o] = h;
        Pl[o] = l;
      }
    }
  }
}

// GEMM2: split-bf16 3-pass: out = Ph*WTh + Ph*WTl + Pl*WTh.
__global__ __launch_bounds__(256, 2) void gemm2(
    const unsigned short* __restrict__ Ph, const unsigned short* __restrict__ Pl,
    const unsigned short* __restrict__ WTh, const unsigned short* __restrict__ WTl,
    float* __restrict__ out) {
  constexpr int K = C_DIM;
  __shared__ unsigned short Ahs[128 * 64];
  __shared__ unsigned short Als[128 * 64];
  __shared__ unsigned short Bhs[128 * 64];
  __shared__ unsigned short Bls[128 * 64];
  const int tid = threadIdx.x;
  const int lane = tid & 63, wave = tid >> 6;
  const int wr = wave >> 1, wc = wave & 1;
  const int nwg = gridDim.x;
  const int cpx = nwg >> 3;
  const int wgid = (blockIdx.x & 7) * cpx + (blockIdx.x >> 3);
  const int bcol = wgid & 15;
  const int brow = wgid >> 4;
  const int fr = lane & 15, fq = lane >> 4;
  f32x4 acc[4][4] = {};

  const char* Ahb = (const char*)(Ph + (size_t)brow * 128 * K);
  const char* Alb = (const char*)(Pl + (size_t)brow * 128 * K);
  const char* Bhb = (const char*)(WTh + (size_t)bcol * 128 * K);
  const char* Blb = (const char*)(WTl + (size_t)bcol * 128 * K);
  for (int kt = 0; kt < K; kt += 64) {
#pragma unroll
    for (int r = 0; r < 4; ++r) {
      int base = r * 4096 + wave * 1024;
      int bo = base + lane * 16;
      int row = bo >> 7;
      int inrow = bo & 127;
      size_t goff = (size_t)row * K * 2 + kt * 2 + inrow;
      load_lds16(Ahb + goff, (char*)Ahs + base);
      load_lds16(Alb + goff, (char*)Als + base);
      load_lds16(Bhb + goff, (char*)Bhs + base);
      load_lds16(Blb + goff, (char*)Bls + base);
    }
    __syncthreads();
#pragma unroll
    for (int ks = 0; ks < 64; ks += 32) {
      bf16x8 ah[4], al[4], bh[4], bl[4];
#pragma unroll
      for (int m = 0; m < 4; ++m) {
        int off = (wr * 64 + m * 16 + fr) * 64 + ks + fq * 8;
        ah[m] = *(const bf16x8*)&Ahs[off];
        al[m] = *(const bf16x8*)&Als[off];
      }
#pragma unroll
      for (int n = 0; n < 4; ++n) {
        int off = (wc * 64 + n * 16 + fr) * 64 + ks + fq * 8;
        bh[n] = *(const bf16x8*)&Bhs[off];
        bl[n] = *(const bf16x8*)&Bls[off];
      }
#pragma unroll
      for (int m = 0; m < 4; ++m)
#pragma unroll
        for (int n = 0; n < 4; ++n)
          acc[m][n] = __builtin_amdgcn_mfma_f32_16x16x32_bf16(ah[m], bh[n], acc[m][n], 0, 0, 0);
#pragma unroll
      for (int m = 0; m < 4; ++m)
#pragma unroll
        for (int n = 0; n < 4; ++n)
          acc[m][n] = __builtin_amdgcn_mfma_f32_16x16x32_bf16(ah[m], bl[n], acc[m][n], 0, 0, 0);
#pragma unroll
      for (int m = 0; m < 4; ++m)
#pragma unroll
        for (int n = 0; n < 4; ++n)
          acc[m][n] = __builtin_amdgcn_mfma_f32_16x16x32_bf16(al[m], bh[n], acc[m][n], 0, 0, 0);
    }
    __syncthreads();
  }
#pragma unroll
  for (int m = 0; m < 4; ++m) {
#pragma unroll
    for (int i = 0; i < 4; ++i) {
      int grow = brow * 128 + wr * 64 + m * 16 + fq * 4 + i;
#pragma unroll
      for (int n = 0; n < 4; ++n) {
        int gcol = bcol * 128 + wc * 64 + n * 16 + fr;
        out[(size_t)grow * C_DIM + gcol] = acc[m][n][i];
      }
    }
  }
}

extern "C" void kernel_launch(void* const* d_in, const int* in_sizes, int n_in,
                              void* d_out, int out_size, void* d_ws, size_t ws_size,
                              hipStream_t stream) {
  const float* X = (const float*)d_in[0];      // [N, D]
  const float* Cen = (const float*)d_in[1];    // [C, D]
  const float* gamma = (const float*)d_in[2];  // [1]
  const float* W = (const float*)d_in[3];      // [C, C]
  float* out = (float*)d_out;                  // [N, C]

  char* ws = (char*)d_ws;
  unsigned short* Xb = (unsigned short*)ws;   ws += (size_t)N_ROWS * D_DIM * 2;  // 64 MiB
  unsigned short* Cb = (unsigned short*)ws;   ws += (size_t)C_DIM * D_DIM * 2;   // 8 MiB
  unsigned short* WTh = (unsigned short*)ws;  ws += (size_t)C_DIM * C_DIM * 2;   // 8 MiB
  unsigned short* WTl = (unsigned short*)ws;  ws += (size_t)C_DIM * C_DIM * 2;   // 8 MiB
  unsigned short* Ph = (unsigned short*)ws;   ws += (size_t)N_ROWS * C_DIM * 2;  // 64 MiB
  unsigned short* Pl = (unsigned short*)ws;   ws += (size_t)N_ROWS * C_DIM * 2;  // 64 MiB
  float* x_sq = (float*)ws;                   ws += (size_t)N_ROWS * 4;
  float* c_sq = (float*)ws;                   ws += (size_t)C_DIM * 4;
  // total ~217 MiB of d_ws

  prep_rows<<<N_ROWS, 256, 0, stream>>>(X, Xb, x_sq);
  prep_rows<<<C_DIM, 256, 0, stream>>>(Cen, Cb, c_sq);
  prep_wt<<<(C_DIM / 64) * (C_DIM / 64), 256, 0, stream>>>(W, WTh, WTl);
  gemm1<<<(N_ROWS / 128) * (C_DIM / 128), 256, 0, stream>>>(Xb, Cb, x_sq, c_sq, gamma, Ph, Pl);
  gemm2<<<(N_ROWS / 128) * (C_DIM / 128), 256, 0, stream>>>(Ph, Pl, WTh, WTl, out);
}

// Round 7
// 718.033 us; speedup vs baseline: 1.0989x; 1.0989x over previous
//
#include <hip/hip_runtime.h>
#include <hip/hip_bf16.h>

// Nystroem: out = exp(-gamma * (||x||^2 + ||c||^2 - 2 X C^T)) @ Wn
// N=16384, D=2048, C=2048, all fp32 in/out.
//
// R6 change (T2): XOR bank swizzle on GEMM LDS tiles.
//   Baseline counters: gemm2 SQ_LDS_BANK_CONFLICT=1.0e8 (~40% of cycles),
//   MfmaUtil 44%, HBM 17% -> LDS-read bound. ds_read_b128 at row*128B had
//   16 lanes/slot (16-way conflict). Swizzle: physical inrow = logical
//   inrow ^ ((row&7)<<4). Applied on the GLOBAL source of global_load_lds
//   (LDS dest must stay linear, rule #21) and on the ds_read address.
//   Bit-identical math; only LDS layout permuted.

#define N_ROWS 16384
#define D_DIM  2048
#define C_DIM  2048

typedef __attribute__((ext_vector_type(4))) float f32x4;
typedef __attribute__((ext_vector_type(8))) short bf16x8;
typedef __attribute__((ext_vector_type(8))) unsigned short ushort8;

__device__ __forceinline__ unsigned short f2bf(float f) {
  unsigned int u = __float_as_uint(f);
  u += 0x7FFFu + ((u >> 16) & 1u);   // RNE
  return (unsigned short)(u >> 16);
}
__device__ __forceinline__ float bf2f(unsigned short h) {
  return __uint_as_float(((unsigned int)h) << 16);
}
__device__ __forceinline__ void load_lds16(const void* g, void* l) {
  __builtin_amdgcn_global_load_lds(
      (const __attribute__((address_space(1))) unsigned int*)g,
      (__attribute__((address_space(3))) unsigned int*)l, 16, 0, 0);
}

// One block per row of `src` (ncols=2048): write bf16 row + sum of squares.
__global__ void prep_rows(const float* __restrict__ src,
                          unsigned short* __restrict__ dst,
                          float* __restrict__ sq) {
  const int row = blockIdx.x;
  const int t = threadIdx.x;
  const float* p = src + (size_t)row * D_DIM + t * 8;
  float4 v0 = ((const float4*)p)[0];
  float4 v1 = ((const float4*)p)[1];
  float vals[8] = {v0.x, v0.y, v0.z, v0.w, v1.x, v1.y, v1.z, v1.w};
  float ss = 0.f;
  ushort8 h;
#pragma unroll
  for (int j = 0; j < 8; ++j) {
    ss += vals[j] * vals[j];
    h[j] = f2bf(vals[j]);
  }
  *(ushort8*)(dst + (size_t)row * D_DIM + t * 8) = h;
  // block reduce ss
  __shared__ float red[4];
  const int lane = t & 63, wave = t >> 6;
#pragma unroll
  for (int off = 32; off > 0; off >>= 1) ss += __shfl_down(ss, off);
  if (lane == 0) red[wave] = ss;
  __syncthreads();
  if (t == 0) sq[row] = red[0] + red[1] + red[2] + red[3];
}

// Transpose + hi/lo split of normalization: WT[j][c] = split(W[c][j]).
__global__ void prep_wt(const float* __restrict__ W,
                        unsigned short* __restrict__ WTh,
                        unsigned short* __restrict__ WTl) {
  __shared__ float tile[64][65];
  const int bc = blockIdx.x >> 5;   // c-tile (rows of W)
  const int bj = blockIdx.x & 31;   // j-tile (cols of W)
  const int t = threadIdx.x;
#pragma unroll
  for (int i = 0; i < 16; ++i) {
    int idx = i * 256 + t;
    int r = idx >> 6, c = idx & 63;
    tile[r][c] = W[(size_t)(bc * 64 + r) * C_DIM + bj * 64 + c];
  }
  __syncthreads();
#pragma unroll
  for (int i = 0; i < 16; ++i) {
    int idx = i * 256 + t;
    int r2 = idx >> 6, c2 = idx & 63;   // r2: j index, c2: c index
    float w = tile[c2][r2];
    unsigned short h = f2bf(w);
    unsigned short l = f2bf(w - bf2f(h));
    size_t o = (size_t)(bj * 64 + r2) * C_DIM + bc * 64 + c2;
    WTh[o] = h;
    WTl[o] = l;
  }
}

// GEMM1: 128x128 tile, BK=64, 4 waves, 16x16x32 bf16 MFMA. LDS XOR-swizzled.
// A = Xb [N][K], B^T = Cb [C][K]. Epilogue: P = exp(-g*dist) -> Ph/Pl.
__global__ __launch_bounds__(256, 2) void gemm1(
    const unsigned short* __restrict__ Xb, const unsigned short* __restrict__ Cb,
    const float* __restrict__ x_sq, const float* __restrict__ c_sq,
    const float* __restrict__ gamma,
    unsigned short* __restrict__ Ph, unsigned short* __restrict__ Pl) {
  constexpr int K = D_DIM;
  __shared__ unsigned short As[128 * 64];
  __shared__ unsigned short Bs[128 * 64];
  const int tid = threadIdx.x;
  const int lane = tid & 63, wave = tid >> 6;
  const int wr = wave >> 1, wc = wave & 1;
  // XCD-aware swizzle: nwg=2048, 8 XCDs, chunk=256 (bijective: 2048%8==0)
  const int nwg = gridDim.x;
  const int cpx = nwg >> 3;
  const int wgid = (blockIdx.x & 7) * cpx + (blockIdx.x >> 3);
  const int bcol = wgid & 15;
  const int brow = wgid >> 4;
  const int fr = lane & 15, fq = lane >> 4;
  f32x4 acc[4][4] = {};
  const float g = gamma[0];

  const char* Abase = (const char*)(Xb + (size_t)brow * 128 * K);
  const char* Bbase = (const char*)(Cb + (size_t)bcol * 128 * K);
  for (int kt = 0; kt < K; kt += 64) {
#pragma unroll
    for (int r = 0; r < 4; ++r) {
      int base = r * 4096 + wave * 1024;  // wave-uniform LDS byte offset
      int bo = base + lane * 16;
      int row = bo >> 7;                           // 128 B per row (64 bf16)
      int inrow = (bo & 127) ^ ((row & 7) << 4);   // inverse-swizzled SOURCE
      load_lds16(Abase + (size_t)row * K * 2 + kt * 2 + inrow, (char*)As + base);
      load_lds16(Bbase + (size_t)row * K * 2 + kt * 2 + inrow, (char*)Bs + base);
    }
    __syncthreads();
#pragma unroll
    for (int ks = 0; ks < 64; ks += 32) {
      bf16x8 af[4], bfr[4];
#pragma unroll
      for (int m = 0; m < 4; ++m) {
        int row = wr * 64 + m * 16 + fr;
        int pb = row * 128 + (((ks + fq * 8) * 2) ^ ((row & 7) << 4));
        af[m] = *(const bf16x8*)((const char*)As + pb);
      }
#pragma unroll
      for (int n = 0; n < 4; ++n) {
        int row = wc * 64 + n * 16 + fr;
        int pb = row * 128 + (((ks + fq * 8) * 2) ^ ((row & 7) << 4));
        bfr[n] = *(const bf16x8*)((const char*)Bs + pb);
      }
#pragma unroll
      for (int m = 0; m < 4; ++m)
#pragma unroll
        for (int n = 0; n < 4; ++n)
          acc[m][n] = __builtin_amdgcn_mfma_f32_16x16x32_bf16(af[m], bfr[n], acc[m][n], 0, 0, 0);
    }
    __syncthreads();
  }
  // epilogue: dist -> exp -> hi/lo bf16
#pragma unroll
  for (int m = 0; m < 4; ++m) {
#pragma unroll
    for (int i = 0; i < 4; ++i) {
      int grow = brow * 128 + wr * 64 + m * 16 + fq * 4 + i;
      float xs = x_sq[grow];
#pragma unroll
      for (int n = 0; n < 4; ++n) {
        int gcol = bcol * 128 + wc * 64 + n * 16 + fr;
        float s = acc[m][n][i];
        float dist = xs + c_sq[gcol] - 2.0f * s;
        float p = __expf(-g * dist);
        unsigned short h = f2bf(p);
        unsigned short l = f2bf(p - bf2f(h));
        size_t o = (size_t)grow * C_DIM + gcol;
        Ph[o] = h;
        Pl[o] = l;
      }
    }
  }
}

// GEMM2: split-bf16 3-pass: out = Ph*WTh + Ph*WTl + Pl*WTh. LDS XOR-swizzled.
__global__ __launch_bounds__(256, 2) void gemm2(
    const unsigned short* __restrict__ Ph, const unsigned short* __restrict__ Pl,
    const unsigned short* __restrict__ WTh, const unsigned short* __restrict__ WTl,
    float* __restrict__ out) {
  constexpr int K = C_DIM;
  __shared__ unsigned short Ahs[128 * 64];
  __shared__ unsigned short Als[128 * 64];
  __shared__ unsigned short Bhs[128 * 64];
  __shared__ unsigned short Bls[128 * 64];
  const int tid = threadIdx.x;
  const int lane = tid & 63, wave = tid >> 6;
  const int wr = wave >> 1, wc = wave & 1;
  const int nwg = gridDim.x;
  const int cpx = nwg >> 3;
  const int wgid = (blockIdx.x & 7) * cpx + (blockIdx.x >> 3);
  const int bcol = wgid & 15;
  const int brow = wgid >> 4;
  const int fr = lane & 15, fq = lane >> 4;
  f32x4 acc[4][4] = {};

  const char* Ahb = (const char*)(Ph + (size_t)brow * 128 * K);
  const char* Alb = (const char*)(Pl + (size_t)brow * 128 * K);
  const char* Bhb = (const char*)(WTh + (size_t)bcol * 128 * K);
  const char* Blb = (const char*)(WTl + (size_t)bcol * 128 * K);
  for (int kt = 0; kt < K; kt += 64) {
#pragma unroll
    for (int r = 0; r < 4; ++r) {
      int base = r * 4096 + wave * 1024;
      int bo = base + lane * 16;
      int row = bo >> 7;
      int inrow = (bo & 127) ^ ((row & 7) << 4);   // inverse-swizzled SOURCE
      size_t goff = (size_t)row * K * 2 + kt * 2 + inrow;
      load_lds16(Ahb + goff, (char*)Ahs + base);
      load_lds16(Alb + goff, (char*)Als + base);
      load_lds16(Bhb + goff, (char*)Bhs + base);
      load_lds16(Blb + goff, (char*)Bls + base);
    }
    __syncthreads();
#pragma unroll
    for (int ks = 0; ks < 64; ks += 32) {
      bf16x8 ah[4], al[4], bh[4], bl[4];
#pragma unroll
      for (int m = 0; m < 4; ++m) {
        int row = wr * 64 + m * 16 + fr;
        int pb = row * 128 + (((ks + fq * 8) * 2) ^ ((row & 7) << 4));
        ah[m] = *(const bf16x8*)((const char*)Ahs + pb);
        al[m] = *(const bf16x8*)((const char*)Als + pb);
      }
#pragma unroll
      for (int n = 0; n < 4; ++n) {
        int row = wc * 64 + n * 16 + fr;
        int pb = row * 128 + (((ks + fq * 8) * 2) ^ ((row & 7) << 4));
        bh[n] = *(const bf16x8*)((const char*)Bhs + pb);
        bl[n] = *(const bf16x8*)((const char*)Bls + pb);
      }
#pragma unroll
      for (int m = 0; m < 4; ++m)
#pragma unroll
        for (int n = 0; n < 4; ++n)
          acc[m][n] = __builtin_amdgcn_mfma_f32_16x16x32_bf16(ah[m], bh[n], acc[m][n], 0, 0, 0);
#pragma unroll
      for (int m = 0; m < 4; ++m)
#pragma unroll
        for (int n = 0; n < 4; ++n)
          acc[m][n] = __builtin_amdgcn_mfma_f32_16x16x32_bf16(ah[m], bl[n], acc[m][n], 0, 0, 0);
#pragma unroll
      for (int m = 0; m < 4; ++m)
#pragma unroll
        for (int n = 0; n < 4; ++n)
          acc[m][n] = __builtin_amdgcn_mfma_f32_16x16x32_bf16(al[m], bh[n], acc[m][n], 0, 0, 0);
    }
    __syncthreads();
  }
#pragma unroll
  for (int m = 0; m < 4; ++m) {
#pragma unroll
    for (int i = 0; i < 4; ++i) {
      int grow = brow * 128 + wr * 64 + m * 16 + fq * 4 + i;
#pragma unroll
      for (int n = 0; n < 4; ++n) {
        int gcol = bcol * 128 + wc * 64 + n * 16 + fr;
        out[(size_t)grow * C_DIM + gcol] = acc[m][n][i];
      }
    }
  }
}

extern "C" void kernel_launch(void* const* d_in, const int* in_sizes, int n_in,
                              void* d_out, int out_size, void* d_ws, size_t ws_size,
                              hipStream_t stream) {
  const float* X = (const float*)d_in[0];      // [N, D]
  const float* Cen = (const float*)d_in[1];    // [C, D]
  const float* gamma = (const float*)d_in[2];  // [1]
  const float* W = (const float*)d_in[3];      // [C, C]
  float* out = (float*)d_out;                  // [N, C]

  char* ws = (char*)d_ws;
  unsigned short* Xb = (unsigned short*)ws;   ws += (size_t)N_ROWS * D_DIM * 2;  // 64 MiB
  unsigned short* Cb = (unsigned short*)ws;   ws += (size_t)C_DIM * D_DIM * 2;   // 8 MiB
  unsigned short* WTh = (unsigned short*)ws;  ws += (size_t)C_DIM * C_DIM * 2;   // 8 MiB
  unsigned short* WTl = (unsigned short*)ws;  ws += (size_t)C_DIM * C_DIM * 2;   // 8 MiB
  unsigned short* Ph = (unsigned short*)ws;   ws += (size_t)N_ROWS * C_DIM * 2;  // 64 MiB
  unsigned short* Pl = (unsigned short*)ws;   ws += (size_t)N_ROWS * C_DIM * 2;  // 64 MiB
  float* x_sq = (float*)ws;                   ws += (size_t)N_ROWS * 4;
  float* c_sq = (float*)ws;                   ws += (size_t)C_DIM * 4;
  // total ~217 MiB of d_ws

  prep_rows<<<N_ROWS, 256, 0, stream>>>(X, Xb, x_sq);
  prep_rows<<<C_DIM, 256, 0, stream>>>(Cen, Cb, c_sq);
  prep_wt<<<(C_DIM / 64) * (C_DIM / 64), 256, 0, stream>>>(W, WTh, WTl);
  gemm1<<<(N_ROWS / 128) * (C_DIM / 128), 256, 0, stream>>>(Xb, Cb, x_sq, c_sq, gamma, Ph, Pl);
  gemm2<<<(N_ROWS / 128) * (C_DIM / 128), 256, 0, stream>>>(Ph, Pl, WTh, WTl, out);
}

// Round 8
// 513.825 us; speedup vs baseline: 1.5357x; 1.3974x over previous
//
#include <hip/hip_runtime.h>
#include <hip/hip_bf16.h>

// Nystroem: out = exp(-gamma * (||x||^2 + ||c||^2 - 2 X C^T)) @ Wn
// N=16384, D=2048, C=2048, all fp32 in/out.
//
// R6 (T2): XOR bank swizzle -> gemm2 bank conflicts 1.0e8 -> 0, MfmaUtil 56.6%.
// R7: bf16 -> fp16 everywhere. All operands range-bounded (X,C ~ N(0,1),
//   P in (0,1], W ~ N(0,1)/45) so fp16's 11-bit mantissa is safe and makes
//   the hi/lo split unnecessary: gemm2 collapses 3 passes -> 1 (1/3 MFMA
//   work, half staging, 32 KB LDS), gemm1 P-store halves, and accuracy
//   IMPROVES (~10x predicted).
//
// Pipeline:
//   prep_rows(X)   -> Xh (fp16), x_sq (fp32)
//   prep_rows(Cen) -> Ch (fp16), c_sq (fp32)
//   prep_wt(Wn)    -> WT (fp16, TRANSPOSED so GEMM2 is B^T form)
//   gemm1: S = Xh @ Ch^T (fp16 MFMA), epilogue P=exp(-g*dist) -> Ph (fp16)
//   gemm2: out = Ph @ WT^T (single-pass fp16 MFMA, fp32 accumulate)

#define N_ROWS 16384
#define D_DIM  2048
#define C_DIM  2048

typedef __attribute__((ext_vector_type(4))) float f32x4;
typedef __attribute__((ext_vector_type(8))) _Float16 f16x8;

__device__ __forceinline__ void load_lds16(const void* g, void* l) {
  __builtin_amdgcn_global_load_lds(
      (const __attribute__((address_space(1))) unsigned int*)g,
      (__attribute__((address_space(3))) unsigned int*)l, 16, 0, 0);
}

// One block per row of `src` (ncols=2048): write fp16 row + sum of squares.
__global__ void prep_rows(const float* __restrict__ src,
                          _Float16* __restrict__ dst,
                          float* __restrict__ sq) {
  const int row = blockIdx.x;
  const int t = threadIdx.x;
  const float* p = src + (size_t)row * D_DIM + t * 8;
  float4 v0 = ((const float4*)p)[0];
  float4 v1 = ((const float4*)p)[1];
  float vals[8] = {v0.x, v0.y, v0.z, v0.w, v1.x, v1.y, v1.z, v1.w};
  float ss = 0.f;
  f16x8 h;
#pragma unroll
  for (int j = 0; j < 8; ++j) {
    ss += vals[j] * vals[j];
    h[j] = (_Float16)vals[j];   // v_cvt_f16_f32, RNE
  }
  *(f16x8*)(dst + (size_t)row * D_DIM + t * 8) = h;
  // block reduce ss
  __shared__ float red[4];
  const int lane = t & 63, wave = t >> 6;
#pragma unroll
  for (int off = 32; off > 0; off >>= 1) ss += __shfl_down(ss, off);
  if (lane == 0) red[wave] = ss;
  __syncthreads();
  if (t == 0) sq[row] = red[0] + red[1] + red[2] + red[3];
}

// Transpose of normalization to fp16: WT[j][c] = (fp16) W[c][j].
__global__ void prep_wt(const float* __restrict__ W,
                        _Float16* __restrict__ WT) {
  __shared__ float tile[64][65];
  const int bc = blockIdx.x >> 5;   // c-tile (rows of W)
  const int bj = blockIdx.x & 31;   // j-tile (cols of W)
  const int t = threadIdx.x;
#pragma unroll
  for (int i = 0; i < 16; ++i) {
    int idx = i * 256 + t;
    int r = idx >> 6, c = idx & 63;
    tile[r][c] = W[(size_t)(bc * 64 + r) * C_DIM + bj * 64 + c];
  }
  __syncthreads();
#pragma unroll
  for (int i = 0; i < 16; ++i) {
    int idx = i * 256 + t;
    int r2 = idx >> 6, c2 = idx & 63;   // r2: j index, c2: c index
    WT[(size_t)(bj * 64 + r2) * C_DIM + bc * 64 + c2] = (_Float16)tile[c2][r2];
  }
}

// GEMM1: 128x128 tile, BK=64, 4 waves, 16x16x32 f16 MFMA. LDS XOR-swizzled.
// A = Xh [N][K], B^T = Ch [C][K]. Epilogue: P = exp(-g*dist) -> Ph (fp16).
__global__ __launch_bounds__(256, 2) void gemm1(
    const _Float16* __restrict__ Xh, const _Float16* __restrict__ Ch,
    const float* __restrict__ x_sq, const float* __restrict__ c_sq,
    const float* __restrict__ gamma,
    _Float16* __restrict__ Ph) {
  constexpr int K = D_DIM;
  __shared__ _Float16 As[128 * 64];
  __shared__ _Float16 Bs[128 * 64];
  const int tid = threadIdx.x;
  const int lane = tid & 63, wave = tid >> 6;
  const int wr = wave >> 1, wc = wave & 1;
  // XCD-aware swizzle: nwg=2048, 8 XCDs, chunk=256 (bijective: 2048%8==0)
  const int nwg = gridDim.x;
  const int cpx = nwg >> 3;
  const int wgid = (blockIdx.x & 7) * cpx + (blockIdx.x >> 3);
  const int bcol = wgid & 15;
  const int brow = wgid >> 4;
  const int fr = lane & 15, fq = lane >> 4;
  f32x4 acc[4][4] = {};
  const float g = gamma[0];

  const char* Abase = (const char*)(Xh + (size_t)brow * 128 * K);
  const char* Bbase = (const char*)(Ch + (size_t)bcol * 128 * K);
  for (int kt = 0; kt < K; kt += 64) {
#pragma unroll
    for (int r = 0; r < 4; ++r) {
      int base = r * 4096 + wave * 1024;  // wave-uniform LDS byte offset
      int bo = base + lane * 16;
      int row = bo >> 7;                           // 128 B per row (64 f16)
      int inrow = (bo & 127) ^ ((row & 7) << 4);   // inverse-swizzled SOURCE
      load_lds16(Abase + (size_t)row * K * 2 + kt * 2 + inrow, (char*)As + base);
      load_lds16(Bbase + (size_t)row * K * 2 + kt * 2 + inrow, (char*)Bs + base);
    }
    __syncthreads();
#pragma unroll
    for (int ks = 0; ks < 64; ks += 32) {
      f16x8 af[4], bfr[4];
#pragma unroll
      for (int m = 0; m < 4; ++m) {
        int row = wr * 64 + m * 16 + fr;
        int pb = row * 128 + (((ks + fq * 8) * 2) ^ ((row & 7) << 4));
        af[m] = *(const f16x8*)((const char*)As + pb);
      }
#pragma unroll
      for (int n = 0; n < 4; ++n) {
        int row = wc * 64 + n * 16 + fr;
        int pb = row * 128 + (((ks + fq * 8) * 2) ^ ((row & 7) << 4));
        bfr[n] = *(const f16x8*)((const char*)Bs + pb);
      }
#pragma unroll
      for (int m = 0; m < 4; ++m)
#pragma unroll
        for (int n = 0; n < 4; ++n)
          acc[m][n] = __builtin_amdgcn_mfma_f32_16x16x32_f16(af[m], bfr[n], acc[m][n], 0, 0, 0);
    }
    __syncthreads();
  }
  // epilogue: dist -> exp -> fp16 P
#pragma unroll
  for (int m = 0; m < 4; ++m) {
#pragma unroll
    for (int i = 0; i < 4; ++i) {
      int grow = brow * 128 + wr * 64 + m * 16 + fq * 4 + i;
      float xs = x_sq[grow];
#pragma unroll
      for (int n = 0; n < 4; ++n) {
        int gcol = bcol * 128 + wc * 64 + n * 16 + fr;
        float s = acc[m][n][i];
        float dist = xs + c_sq[gcol] - 2.0f * s;
        float p = __expf(-g * dist);
        Ph[(size_t)grow * C_DIM + gcol] = (_Float16)p;
      }
    }
  }
}

// GEMM2: single-pass fp16: out = Ph @ WT^T, fp32 accumulate. LDS XOR-swizzled.
__global__ __launch_bounds__(256, 2) void gemm2(
    const _Float16* __restrict__ Ph, const _Float16* __restrict__ WT,
    float* __restrict__ out) {
  constexpr int K = C_DIM;
  __shared__ _Float16 As[128 * 64];
  __shared__ _Float16 Bs[128 * 64];
  const int tid = threadIdx.x;
  const int lane = tid & 63, wave = tid >> 6;
  const int wr = wave >> 1, wc = wave & 1;
  const int nwg = gridDim.x;
  const int cpx = nwg >> 3;
  const int wgid = (blockIdx.x & 7) * cpx + (blockIdx.x >> 3);
  const int bcol = wgid & 15;
  const int brow = wgid >> 4;
  const int fr = lane & 15, fq = lane >> 4;
  f32x4 acc[4][4] = {};

  const char* Abase = (const char*)(Ph + (size_t)brow * 128 * K);
  const char* Bbase = (const char*)(WT + (size_t)bcol * 128 * K);
  for (int kt = 0; kt < K; kt += 64) {
#pragma unroll
    for (int r = 0; r < 4; ++r) {
      int base = r * 4096 + wave * 1024;
      int bo = base + lane * 16;
      int row = bo >> 7;
      int inrow = (bo & 127) ^ ((row & 7) << 4);   // inverse-swizzled SOURCE
      load_lds16(Abase + (size_t)row * K * 2 + kt * 2 + inrow, (char*)As + base);
      load_lds16(Bbase + (size_t)row * K * 2 + kt * 2 + inrow, (char*)Bs + base);
    }
    __syncthreads();
#pragma unroll
    for (int ks = 0; ks < 64; ks += 32) {
      f16x8 af[4], bfr[4];
#pragma unroll
      for (int m = 0; m < 4; ++m) {
        int row = wr * 64 + m * 16 + fr;
        int pb = row * 128 + (((ks + fq * 8) * 2) ^ ((row & 7) << 4));
        af[m] = *(const f16x8*)((const char*)As + pb);
      }
#pragma unroll
      for (int n = 0; n < 4; ++n) {
        int row = wc * 64 + n * 16 + fr;
        int pb = row * 128 + (((ks + fq * 8) * 2) ^ ((row & 7) << 4));
        bfr[n] = *(const f16x8*)((const char*)Bs + pb);
      }
#pragma unroll
      for (int m = 0; m < 4; ++m)
#pragma unroll
        for (int n = 0; n < 4; ++n)
          acc[m][n] = __builtin_amdgcn_mfma_f32_16x16x32_f16(af[m], bfr[n], acc[m][n], 0, 0, 0);
    }
    __syncthreads();
  }
#pragma unroll
  for (int m = 0; m < 4; ++m) {
#pragma unroll
    for (int i = 0; i < 4; ++i) {
      int grow = brow * 128 + wr * 64 + m * 16 + fq * 4 + i;
#pragma unroll
      for (int n = 0; n < 4; ++n) {
        int gcol = bcol * 128 + wc * 64 + n * 16 + fr;
        out[(size_t)grow * C_DIM + gcol] = acc[m][n][i];
      }
    }
  }
}

extern "C" void kernel_launch(void* const* d_in, const int* in_sizes, int n_in,
                              void* d_out, int out_size, void* d_ws, size_t ws_size,
                              hipStream_t stream) {
  const float* X = (const float*)d_in[0];      // [N, D]
  const float* Cen = (const float*)d_in[1];    // [C, D]
  const float* gamma = (const float*)d_in[2];  // [1]
  const float* W = (const float*)d_in[3];      // [C, C]
  float* out = (float*)d_out;                  // [N, C]

  char* ws = (char*)d_ws;
  _Float16* Xh = (_Float16*)ws;  ws += (size_t)N_ROWS * D_DIM * 2;  // 64 MiB
  _Float16* Ch = (_Float16*)ws;  ws += (size_t)C_DIM * D_DIM * 2;   // 8 MiB
  _Float16* WT = (_Float16*)ws;  ws += (size_t)C_DIM * C_DIM * 2;   // 8 MiB
  _Float16* Ph = (_Float16*)ws;  ws += (size_t)N_ROWS * C_DIM * 2;  // 64 MiB
  float* x_sq = (float*)ws;      ws += (size_t)N_ROWS * 4;
  float* c_sq = (float*)ws;      ws += (size_t)C_DIM * 4;
  // total ~144 MiB of d_ws

  prep_rows<<<N_ROWS, 256, 0, stream>>>(X, Xh, x_sq);
  prep_rows<<<C_DIM, 256, 0, stream>>>(Cen, Ch, c_sq);
  prep_wt<<<(C_DIM / 64) * (C_DIM / 64), 256, 0, stream>>>(W, WT);
  gemm1<<<(N_ROWS / 128) * (C_DIM / 128), 256, 0, stream>>>(Xh, Ch, x_sq, c_sq, gamma, Ph);
  gemm2<<<(N_ROWS / 128) * (C_DIM / 128), 256, 0, stream>>>(Ph, WT, out);
}

// Round 14
// 509.839 us; speedup vs baseline: 1.5477x; 1.0078x over previous
//
#include <hip/hip_runtime.h>
#include <hip/hip_bf16.h>

// Nystroem: out = exp(-gamma * (||x||^2 + ||c||^2 - 2 X C^T)) @ Wn
// N=16384, D=2048, C=2048, all fp32 in/out.
//
// R6: T2 XOR swizzle (conflicts 1e8 -> 0). R7: fp16 single-pass (514 us).
// R8: 256x256 tile, BK=32, RING-4 LDS, counted-vmcnt deep pipeline.
//   - 512 thr / 8 waves (2M x 4N), per-wave out 128x64, acc 8x4 f32x4.
//   - LDS 128 KB dynamic: A-ring 4x16KB + B-ring 4x16KB.
//   - Per K-tile: vmcnt(8) [never drains; t+1,t+2 in flight] + 1 barrier,
//     then issue tile t+3 into the slot the barrier just freed.
//   - Row-pair LDS layout: line = 2 rows x 32k, XOR ((line&7)<<4) -> every
//     16-lane frag read spreads over all 8 slots, 2 lanes/slot = free.
//   - setprio(1) around the 32-MFMA cluster.

#define N_ROWS 16384
#define D_DIM  2048
#define C_DIM  2048
#define KBYTES (D_DIM * 2)   // 4096, same for both gemms (K=2048 fp16)
#define NT     64            // K / 32

typedef __attribute__((ext_vector_type(4))) float f32x4;
typedef __attribute__((ext_vector_type(8))) _Float16 f16x8;
typedef __attribute__((ext_vector_type(4))) _Float16 f16x4;

__device__ __forceinline__ void load_lds16(const void* g, void* l) {
  __builtin_amdgcn_global_load_lds(
      (const __attribute__((address_space(1))) unsigned int*)g,
      (__attribute__((address_space(3))) unsigned int*)l, 16, 0, 0);
}

// ---------------- prep kernels ----------------
// wave-per-row: 4 waves/block, one 2048-col row each. No LDS, no syncthreads.
__global__ void prep_rows(const float* __restrict__ src,
                          _Float16* __restrict__ dst,
                          float* __restrict__ sq) {
  const int wid = threadIdx.x >> 6, lane = threadIdx.x & 63;
  const int row = blockIdx.x * 4 + wid;
  const float4* p = (const float4*)(src + (size_t)row * D_DIM);
  _Float16* d = dst + (size_t)row * D_DIM;
  float ss = 0.f;
#pragma unroll
  for (int rep = 0; rep < 8; ++rep) {
    float4 v = p[rep * 64 + lane];
    ss += v.x * v.x + v.y * v.y + v.z * v.z + v.w * v.w;
    f16x4 h;
    h[0] = (_Float16)v.x; h[1] = (_Float16)v.y;
    h[2] = (_Float16)v.z; h[3] = (_Float16)v.w;
    *(f16x4*)(d + (rep * 64 + lane) * 4) = h;
  }
#pragma unroll
  for (int off = 32; off > 0; off >>= 1) ss += __shfl_down(ss, off);
  if (lane == 0) sq[row] = ss;
}

// Transpose of normalization to fp16: WT[j][c] = (fp16) W[c][j].
__global__ void prep_wt(const float* __restrict__ W,
                        _Float16* __restrict__ WT) {
  __shared__ float tile[64][65];
  const int bc = blockIdx.x >> 5;
  const int bj = blockIdx.x & 31;
  const int t = threadIdx.x;
#pragma unroll
  for (int i = 0; i < 16; ++i) {
    int idx = i * 256 + t;
    int r = idx >> 6, c = idx & 63;
    tile[r][c] = W[(size_t)(bc * 64 + r) * C_DIM + bj * 64 + c];
  }
  __syncthreads();
#pragma unroll
  for (int i = 0; i < 16; ++i) {
    int idx = i * 256 + t;
    int r2 = idx >> 6, c2 = idx & 63;
    WT[(size_t)(bj * 64 + r2) * C_DIM + bc * 64 + c2] = (_Float16)tile[c2][r2];
  }
}

// ---------------- GEMM core: 256x256, BK=32, ring-4, counted vmcnt ----------
// LDS slot layout (16 KB per operand per slot): line L (128 B) holds rows
// {2L, 2L+1} k 0..31; physical within-line byte = logical ^ ((L&7)<<4).
__device__ __forceinline__ void gemm_core(
    const char* Abase, const char* Bbase, char* smem,
    int wid, int lane, f32x4 (&acc)[8][4]) {
  const int wm = wid >> 2, wn = wid & 3;
  const int fr = lane & 15, fq = lane >> 4;
  // staging decode: LDS-linear d -> (row, k-byte), inverse-swizzled global src
  int srcoff[2], dstoff[2];
#pragma unroll
  for (int q = 0; q < 2; ++q) {
    int d = q * 8192 + wid * 1024 + lane * 16;
    int line = d >> 7;
    int un = (d & 127) ^ ((line & 7) << 4);
    int r = line * 2 + (un >> 6);
    srcoff[q] = r * KBYTES + (un & 63);
    dstoff[q] = q * 8192 + wid * 1024;   // wave-uniform dest base
  }
  // fragment ds_read physical offsets within a slot
  int aoff[8], boff[4];
#pragma unroll
  for (int m = 0; m < 8; ++m) {
    int r = wm * 128 + m * 16 + fr;
    int line = r >> 1;
    aoff[m] = line * 128 + ((((r & 1) << 6) | (fq << 4)) ^ ((line & 7) << 4));
  }
#pragma unroll
  for (int n = 0; n < 4; ++n) {
    int r = wn * 64 + n * 16 + fr;
    int line = r >> 1;
    boff[n] = line * 128 + ((((r & 1) << 6) | (fq << 4)) ^ ((line & 7) << 4));
  }
  char* As = smem;             // 4 x 16 KB
  char* Bs = smem + 65536;     // 4 x 16 KB
  // prologue: issue tiles 0,1,2 (slots 0,1,2)
  for (int tt = 0; tt < 3; ++tt) {
#pragma unroll
    for (int q = 0; q < 2; ++q) {
      load_lds16(Abase + (size_t)(srcoff[q] + tt * 64), As + tt * 16384 + dstoff[q]);
      load_lds16(Bbase + (size_t)(srcoff[q] + tt * 64), Bs + tt * 16384 + dstoff[q]);
    }
  }
  for (int t = 0; t < NT; ++t) {
    // certify tile t landed (own stream; t+1,t+2 = 8 loads may remain)
    int rem = NT - 1 - t;
    if (rem >= 2)      asm volatile("s_waitcnt vmcnt(8)" ::: "memory");
    else if (rem == 1) asm volatile("s_waitcnt vmcnt(4)" ::: "memory");
    else               asm volatile("s_waitcnt vmcnt(0)" ::: "memory");
    __builtin_amdgcn_sched_barrier(0);
    __builtin_amdgcn_s_barrier();   // tile t readable everywhere; t-1 consumed
    __builtin_amdgcn_sched_barrier(0);
    if (t + 3 < NT) {               // issue t+3 into slot (t+3)&3 (just freed)
      int ns = (t + 3) & 3;
#pragma unroll
      for (int q = 0; q < 2; ++q) {
        load_lds16(Abase + (size_t)(srcoff[q] + (t + 3) * 64), As + ns * 16384 + dstoff[q]);
        load_lds16(Bbase + (size_t)(srcoff[q] + (t + 3) * 64), Bs + ns * 16384 + dstoff[q]);
      }
    }
    __builtin_amdgcn_sched_barrier(0);
    const char* Aslot = As + (t & 3) * 16384;
    const char* Bslot = Bs + (t & 3) * 16384;
    f16x8 b0 = *(const f16x8*)(Bslot + boff[0]);
    f16x8 b1 = *(const f16x8*)(Bslot + boff[1]);
    f16x8 b2 = *(const f16x8*)(Bslot + boff[2]);
    f16x8 b3 = *(const f16x8*)(Bslot + boff[3]);
    __builtin_amdgcn_s_setprio(1);
#pragma unroll
    for (int m = 0; m < 8; ++m) {
      f16x8 a = *(const f16x8*)(Aslot + aoff[m]);
      acc[m][0] = __builtin_amdgcn_mfma_f32_16x16x32_f16(a, b0, acc[m][0], 0, 0, 0);
      acc[m][1] = __builtin_amdgcn_mfma_f32_16x16x32_f16(a, b1, acc[m][1], 0, 0, 0);
      acc[m][2] = __builtin_amdgcn_mfma_f32_16x16x32_f16(a, b2, acc[m][2], 0, 0, 0);
      acc[m][3] = __builtin_amdgcn_mfma_f32_16x16x32_f16(a, b3, acc[m][3], 0, 0, 0);
    }
    __builtin_amdgcn_s_setprio(0);
  }
}

// GEMM1: S = Xh @ Ch^T, epilogue P = exp(-g*dist) -> Ph (fp16).
__global__ __launch_bounds__(512, 2) void gemm1(
    const _Float16* __restrict__ Xh, const _Float16* __restrict__ Ch,
    const float* __restrict__ x_sq, const float* __restrict__ c_sq,
    const float* __restrict__ gamma,
    _Float16* __restrict__ Ph) {
  extern __shared__ char smem[];
  const int tid = threadIdx.x;
  const int lane = tid & 63, wid = tid >> 6;
  const int nwg = gridDim.x;                 // 512, %8==0 -> bijective
  const int cpx = nwg >> 3;
  const int wgid = (blockIdx.x & 7) * cpx + (blockIdx.x >> 3);
  const int bcol = wgid & 7;                 // 8 col tiles
  const int brow = wgid >> 3;                // 64 row tiles
  const int wm = wid >> 2, wn = wid & 3;
  const int fr = lane & 15, fq = lane >> 4;
  f32x4 acc[8][4] = {};
  const float g = gamma[0];

  gemm_core((const char*)(Xh + (size_t)brow * 256 * D_DIM),
            (const char*)(Ch + (size_t)bcol * 256 * D_DIM),
            smem, wid, lane, acc);

  float cs[4];
#pragma unroll
  for (int n = 0; n < 4; ++n)
    cs[n] = c_sq[bcol * 256 + wn * 64 + n * 16 + fr];
#pragma unroll
  for (int m = 0; m < 8; ++m) {
#pragma unroll
    for (int i = 0; i < 4; ++i) {
      int grow = brow * 256 + wm * 128 + m * 16 + fq * 4 + i;
      float xs = x_sq[grow];
#pragma unroll
      for (int n = 0; n < 4; ++n) {
        int gcol = bcol * 256 + wn * 64 + n * 16 + fr;
        float dist = xs + cs[n] - 2.0f * acc[m][n][i];
        Ph[(size_t)grow * C_DIM + gcol] = (_Float16)__expf(-g * dist);
      }
    }
  }
}

// GEMM2: out = Ph @ WT^T (fp32 accumulate, fp32 store).
__global__ __launch_bounds__(512, 2) void gemm2(
    const _Float16* __restrict__ Ph, const _Float16* __restrict__ WT,
    float* __restrict__ out) {
  extern __shared__ char smem[];
  const int tid = threadIdx.x;
  const int lane = tid & 63, wid = tid >> 6;
  const int nwg = gridDim.x;
  const int cpx = nwg >> 3;
  const int wgid = (blockIdx.x & 7) * cpx + (blockIdx.x >> 3);
  const int bcol = wgid & 7;
  const int brow = wgid >> 3;
  const int wm = wid >> 2, wn = wid & 3;
  const int fr = lane & 15, fq = lane >> 4;
  f32x4 acc[8][4] = {};

  gemm_core((const char*)(Ph + (size_t)brow * 256 * C_DIM),
            (const char*)(WT + (size_t)bcol * 256 * C_DIM),
            smem, wid, lane, acc);

#pragma unroll
  for (int m = 0; m < 8; ++m) {
#pragma unroll
    for (int i = 0; i < 4; ++i) {
      int grow = brow * 256 + wm * 128 + m * 16 + fq * 4 + i;
#pragma unroll
      for (int n = 0; n < 4; ++n) {
        int gcol = bcol * 256 + wn * 64 + n * 16 + fr;
        out[(size_t)grow * C_DIM + gcol] = acc[m][n][i];
      }
    }
  }
}

extern "C" void kernel_launch(void* const* d_in, const int* in_sizes, int n_in,
                              void* d_out, int out_size, void* d_ws, size_t ws_size,
                              hipStream_t stream) {
  const float* X = (const float*)d_in[0];
  const float* Cen = (const float*)d_in[1];
  const float* gamma = (const float*)d_in[2];
  const float* W = (const float*)d_in[3];
  float* out = (float*)d_out;

  char* ws = (char*)d_ws;
  _Float16* Xh = (_Float16*)ws;  ws += (size_t)N_ROWS * D_DIM * 2;  // 64 MiB
  _Float16* Ch = (_Float16*)ws;  ws += (size_t)C_DIM * D_DIM * 2;   // 8 MiB
  _Float16* WT = (_Float16*)ws;  ws += (size_t)C_DIM * C_DIM * 2;   // 8 MiB
  _Float16* Ph = (_Float16*)ws;  ws += (size_t)N_ROWS * C_DIM * 2;  // 64 MiB
  float* x_sq = (float*)ws;      ws += (size_t)N_ROWS * 4;
  float* c_sq = (float*)ws;      ws += (size_t)C_DIM * 4;

  // allow 128 KB dynamic LDS (idempotent, not a stream op)
  (void)hipFuncSetAttribute((const void*)gemm1,
      hipFuncAttributeMaxDynamicSharedMemorySize, 131072);
  (void)hipFuncSetAttribute((const void*)gemm2,
      hipFuncAttributeMaxDynamicSharedMemorySize, 131072);

  prep_rows<<<N_ROWS / 4, 256, 0, stream>>>(X, Xh, x_sq);
  prep_rows<<<C_DIM / 4, 256, 0, stream>>>(Cen, Ch, c_sq);
  prep_wt<<<(C_DIM / 64) * (C_DIM / 64), 256, 0, stream>>>(W, WT);
  gemm1<<<(N_ROWS / 256) * (C_DIM / 256), 512, 131072, stream>>>(Xh, Ch, x_sq, c_sq, gamma, Ph);
  gemm2<<<(N_ROWS / 256) * (C_DIM / 256), 512, 131072, stream>>>(Ph, WT, out);
}

// Round 15
// 502.757 us; speedup vs baseline: 1.5695x; 1.0141x over previous
//
#include <hip/hip_runtime.h>
#include <hip/hip_bf16.h>

// Nystroem: out = exp(-gamma * (||x||^2 + ||c||^2 - 2 X C^T)) @ Wn
// N=16384, D=2048, C=2048, all fp32 in/out.
//
// R6: T2 XOR swizzle (conflicts 1e8 -> 0). R7: fp16 single-pass (514 us).
// R8: 256x256 / BK=32 / ring-4 / counted vmcnt: NEUTRAL (510 us, MfmaUtil
//     42% < falsifier 52%). Diagnosis: ds_reads sat AFTER the barrier,
//     putting ~150cy LDS latency on every iteration's critical path, and
//     1 block/CU lockstep gave no cross-block overlap to hide it.
// R9 (this): m201 phase order -- fragment ds_reads issued BEFORE the
//     barrier (tile certified by the PREVIOUS barrier), so read latency
//     spans the barrier; vmcnt(4) steady state; stage after barrier.

#define N_ROWS 16384
#define D_DIM  2048
#define C_DIM  2048
#define KBYTES (D_DIM * 2)   // 4096, same for both gemms (K=2048 fp16)
#define NT     64            // K / 32

typedef __attribute__((ext_vector_type(4))) float f32x4;
typedef __attribute__((ext_vector_type(8))) _Float16 f16x8;
typedef __attribute__((ext_vector_type(4))) _Float16 f16x4;

__device__ __forceinline__ void load_lds16(const void* g, void* l) {
  __builtin_amdgcn_global_load_lds(
      (const __attribute__((address_space(1))) unsigned int*)g,
      (__attribute__((address_space(3))) unsigned int*)l, 16, 0, 0);
}

// ---------------- prep kernels ----------------
__global__ void prep_rows(const float* __restrict__ src,
                          _Float16* __restrict__ dst,
                          float* __restrict__ sq) {
  const int wid = threadIdx.x >> 6, lane = threadIdx.x & 63;
  const int row = blockIdx.x * 4 + wid;
  const float4* p = (const float4*)(src + (size_t)row * D_DIM);
  _Float16* d = dst + (size_t)row * D_DIM;
  float ss = 0.f;
#pragma unroll
  for (int rep = 0; rep < 8; ++rep) {
    float4 v = p[rep * 64 + lane];
    ss += v.x * v.x + v.y * v.y + v.z * v.z + v.w * v.w;
    f16x4 h;
    h[0] = (_Float16)v.x; h[1] = (_Float16)v.y;
    h[2] = (_Float16)v.z; h[3] = (_Float16)v.w;
    *(f16x4*)(d + (rep * 64 + lane) * 4) = h;
  }
#pragma unroll
  for (int off = 32; off > 0; off >>= 1) ss += __shfl_down(ss, off);
  if (lane == 0) sq[row] = ss;
}

__global__ void prep_wt(const float* __restrict__ W,
                        _Float16* __restrict__ WT) {
  __shared__ float tile[64][65];
  const int bc = blockIdx.x >> 5;
  const int bj = blockIdx.x & 31;
  const int t = threadIdx.x;
#pragma unroll
  for (int i = 0; i < 16; ++i) {
    int idx = i * 256 + t;
    int r = idx >> 6, c = idx & 63;
    tile[r][c] = W[(size_t)(bc * 64 + r) * C_DIM + bj * 64 + c];
  }
  __syncthreads();
#pragma unroll
  for (int i = 0; i < 16; ++i) {
    int idx = i * 256 + t;
    int r2 = idx >> 6, c2 = idx & 63;
    WT[(size_t)(bj * 64 + r2) * C_DIM + bc * 64 + c2] = (_Float16)tile[c2][r2];
  }
}

// ---------------- GEMM core: 256x256, BK=32, ring-4, reads-before-barrier --
// LDS slot layout (16 KB per operand per slot): line L (128 B) holds rows
// {2L, 2L+1} k 0..31; physical within-line byte = logical ^ ((L&7)<<4).
//
// Loop invariant at top of iter t: tiles t..t+2 issued; tile t published by
// the barrier at the end of iter t-1 (prologue barrier for t=0).
//   (a) ds_read 12 fragments of tile t           [latency spans barrier]
//   (b) vmcnt(4): certify own tile-t+1 loads     [(0) for t>=NT-2]
//   (c) s_barrier: publish t+1; free slot (t-1)&3
//   (d) stage tile t+3 into slot (t+3)&3
//   (e) lgkm (compiler) + setprio + 32 MFMA
__device__ __forceinline__ void gemm_core(
    const char* Abase, const char* Bbase, char* smem,
    int wid, int lane, f32x4 (&acc)[8][4]) {
  const int wm = wid >> 2, wn = wid & 3;
  const int fr = lane & 15, fq = lane >> 4;
  int srcoff[2], dstoff[2];
#pragma unroll
  for (int q = 0; q < 2; ++q) {
    int d = q * 8192 + wid * 1024 + lane * 16;
    int line = d >> 7;
    int un = (d & 127) ^ ((line & 7) << 4);
    int r = line * 2 + (un >> 6);
    srcoff[q] = r * KBYTES + (un & 63);
    dstoff[q] = q * 8192 + wid * 1024;   // wave-uniform dest base
  }
  int aoff[8], boff[4];
#pragma unroll
  for (int m = 0; m < 8; ++m) {
    int r = wm * 128 + m * 16 + fr;
    int line = r >> 1;
    aoff[m] = line * 128 + ((((r & 1) << 6) | (fq << 4)) ^ ((line & 7) << 4));
  }
#pragma unroll
  for (int n = 0; n < 4; ++n) {
    int r = wn * 64 + n * 16 + fr;
    int line = r >> 1;
    boff[n] = line * 128 + ((((r & 1) << 6) | (fq << 4)) ^ ((line & 7) << 4));
  }
  char* As = smem;             // 4 x 16 KB
  char* Bs = smem + 65536;     // 4 x 16 KB
  // prologue: issue tiles 0,1,2; certify tile 0; publish it
  for (int tt = 0; tt < 3; ++tt) {
#pragma unroll
    for (int q = 0; q < 2; ++q) {
      load_lds16(Abase + (size_t)(srcoff[q] + tt * 64), As + tt * 16384 + dstoff[q]);
      load_lds16(Bbase + (size_t)(srcoff[q] + tt * 64), Bs + tt * 16384 + dstoff[q]);
    }
  }
  asm volatile("s_waitcnt vmcnt(8)" ::: "memory");
  __builtin_amdgcn_sched_barrier(0);
  __builtin_amdgcn_s_barrier();
  __builtin_amdgcn_sched_barrier(0);

  for (int t = 0; t < NT; ++t) {
    const char* Aslot = As + (t & 3) * 16384;
    const char* Bslot = Bs + (t & 3) * 16384;
    // (a) fragment reads of tile t (published by previous barrier)
    f16x8 b0 = *(const f16x8*)(Bslot + boff[0]);
    f16x8 b1 = *(const f16x8*)(Bslot + boff[1]);
    f16x8 b2 = *(const f16x8*)(Bslot + boff[2]);
    f16x8 b3 = *(const f16x8*)(Bslot + boff[3]);
    f16x8 a[8];
#pragma unroll
    for (int m = 0; m < 8; ++m) a[m] = *(const f16x8*)(Aslot + aoff[m]);
    __builtin_amdgcn_sched_barrier(0);
    // (b) certify next tile's loads (own stream)
    if (t < NT - 2) asm volatile("s_waitcnt vmcnt(4)" ::: "memory");
    else            asm volatile("s_waitcnt vmcnt(0)" ::: "memory");
    __builtin_amdgcn_sched_barrier(0);
    // (c) publish tile t+1; slot (t-1)&3 now free
    __builtin_amdgcn_s_barrier();
    __builtin_amdgcn_sched_barrier(0);
    // (d) stage tile t+3
    if (t + 3 < NT) {
      int ns = (t + 3) & 3;
#pragma unroll
      for (int q = 0; q < 2; ++q) {
        load_lds16(Abase + (size_t)(srcoff[q] + (t + 3) * 64), As + ns * 16384 + dstoff[q]);
        load_lds16(Bbase + (size_t)(srcoff[q] + (t + 3) * 64), Bs + ns * 16384 + dstoff[q]);
      }
    }
    __builtin_amdgcn_sched_barrier(0);
    // (e) MFMA cluster (compiler inserts lgkmcnt before first use)
    __builtin_amdgcn_s_setprio(1);
#pragma unroll
    for (int m = 0; m < 8; ++m) {
      acc[m][0] = __builtin_amdgcn_mfma_f32_16x16x32_f16(a[m], b0, acc[m][0], 0, 0, 0);
      acc[m][1] = __builtin_amdgcn_mfma_f32_16x16x32_f16(a[m], b1, acc[m][1], 0, 0, 0);
      acc[m][2] = __builtin_amdgcn_mfma_f32_16x16x32_f16(a[m], b2, acc[m][2], 0, 0, 0);
      acc[m][3] = __builtin_amdgcn_mfma_f32_16x16x32_f16(a[m], b3, acc[m][3], 0, 0, 0);
    }
    __builtin_amdgcn_s_setprio(0);
  }
}

// GEMM1: S = Xh @ Ch^T, epilogue P = exp(-g*dist) -> Ph (fp16).
__global__ __launch_bounds__(512, 2) void gemm1(
    const _Float16* __restrict__ Xh, const _Float16* __restrict__ Ch,
    const float* __restrict__ x_sq, const float* __restrict__ c_sq,
    const float* __restrict__ gamma,
    _Float16* __restrict__ Ph) {
  extern __shared__ char smem[];
  const int tid = threadIdx.x;
  const int lane = tid & 63, wid = tid >> 6;
  const int nwg = gridDim.x;                 // 512, %8==0 -> bijective
  const int cpx = nwg >> 3;
  const int wgid = (blockIdx.x & 7) * cpx + (blockIdx.x >> 3);
  const int bcol = wgid & 7;
  const int brow = wgid >> 3;
  const int wm = wid >> 2, wn = wid & 3;
  const int fr = lane & 15, fq = lane >> 4;
  f32x4 acc[8][4] = {};
  const float g = gamma[0];

  gemm_core((const char*)(Xh + (size_t)brow * 256 * D_DIM),
            (const char*)(Ch + (size_t)bcol * 256 * D_DIM),
            smem, wid, lane, acc);

  float cs[4];
#pragma unroll
  for (int n = 0; n < 4; ++n)
    cs[n] = c_sq[bcol * 256 + wn * 64 + n * 16 + fr];
#pragma unroll
  for (int m = 0; m < 8; ++m) {
#pragma unroll
    for (int i = 0; i < 4; ++i) {
      int grow = brow * 256 + wm * 128 + m * 16 + fq * 4 + i;
      float xs = x_sq[grow];
#pragma unroll
      for (int n = 0; n < 4; ++n) {
        int gcol = bcol * 256 + wn * 64 + n * 16 + fr;
        float dist = xs + cs[n] - 2.0f * acc[m][n][i];
        Ph[(size_t)grow * C_DIM + gcol] = (_Float16)__expf(-g * dist);
      }
    }
  }
}

// GEMM2: out = Ph @ WT^T (fp32 accumulate, fp32 store).
__global__ __launch_bounds__(512, 2) void gemm2(
    const _Float16* __restrict__ Ph, const _Float16* __restrict__ WT,
    float* __restrict__ out) {
  extern __shared__ char smem[];
  const int tid = threadIdx.x;
  const int lane = tid & 63, wid = tid >> 6;
  const int nwg = gridDim.x;
  const int cpx = nwg >> 3;
  const int wgid = (blockIdx.x & 7) * cpx + (blockIdx.x >> 3);
  const int bcol = wgid & 7;
  const int brow = wgid >> 3;
  const int wm = wid >> 2, wn = wid & 3;
  const int fr = lane & 15, fq = lane >> 4;
  f32x4 acc[8][4] = {};

  gemm_core((const char*)(Ph + (size_t)brow * 256 * C_DIM),
            (const char*)(WT + (size_t)bcol * 256 * C_DIM),
            smem, wid, lane, acc);

#pragma unroll
  for (int m = 0; m < 8; ++m) {
#pragma unroll
    for (int i = 0; i < 4; ++i) {
      int grow = brow * 256 + wm * 128 + m * 16 + fq * 4 + i;
#pragma unroll
      for (int n = 0; n < 4; ++n) {
        int gcol = bcol * 256 + wn * 64 + n * 16 + fr;
        out[(size_t)grow * C_DIM + gcol] = acc[m][n][i];
      }
    }
  }
}

extern "C" void kernel_launch(void* const* d_in, const int* in_sizes, int n_in,
                              void* d_out, int out_size, void* d_ws, size_t ws_size,
                              hipStream_t stream) {
  const float* X = (const float*)d_in[0];
  const float* Cen = (const float*)d_in[1];
  const float* gamma = (const float*)d_in[2];
  const float* W = (const float*)d_in[3];
  float* out = (float*)d_out;

  char* ws = (char*)d_ws;
  _Float16* Xh = (_Float16*)ws;  ws += (size_t)N_ROWS * D_DIM * 2;  // 64 MiB
  _Float16* Ch = (_Float16*)ws;  ws += (size_t)C_DIM * D_DIM * 2;   // 8 MiB
  _Float16* WT = (_Float16*)ws;  ws += (size_t)C_DIM * C_DIM * 2;   // 8 MiB
  _Float16* Ph = (_Float16*)ws;  ws += (size_t)N_ROWS * C_DIM * 2;  // 64 MiB
  float* x_sq = (float*)ws;      ws += (size_t)N_ROWS * 4;
  float* c_sq = (float*)ws;      ws += (size_t)C_DIM * 4;

  (void)hipFuncSetAttribute((const void*)gemm1,
      hipFuncAttributeMaxDynamicSharedMemorySize, 131072);
  (void)hipFuncSetAttribute((const void*)gemm2,
      hipFuncAttributeMaxDynamicSharedMemorySize, 131072);

  prep_rows<<<N_ROWS / 4, 256, 0, stream>>>(X, Xh, x_sq);
  prep_rows<<<C_DIM / 4, 256, 0, stream>>>(Cen, Ch, c_sq);
  prep_wt<<<(C_DIM / 64) * (C_DIM / 64), 256, 0, stream>>>(W, WT);
  gemm1<<<(N_ROWS / 256) * (C_DIM / 256), 512, 131072, stream>>>(Xh, Ch, x_sq, c_sq, gamma, Ph);
  gemm2<<<(N_ROWS / 256) * (C_DIM / 256), 512, 131072, stream>>>(Ph, WT, out);
}